// Round 2
// baseline (273.843 us; speedup 1.0000x reference)
//
#include <hip/hip_runtime.h>
#include <hip/hip_bf16.h>

#define S_LEN 1024
#define DH 64
#define QB 64      // q rows per workgroup
#define KT 64      // k rows per tile
#define NKT 16     // S_LEN / KT
#define LDP 72     // padded LDS row length (bf16 elems)

typedef __attribute__((ext_vector_type(8))) short bf16x8;
typedef __attribute__((ext_vector_type(4))) float f32x4;

__device__ __forceinline__ unsigned short f2bf(float f) {
  unsigned u = __float_as_uint(f);
  u = u + 0x7FFFu + ((u >> 16) & 1u);   // round-to-nearest-even
  return (unsigned short)(u >> 16);
}

// pack 2 f32 -> 2 bf16 (RNE) in one dword; should emit v_cvt_pk_bf16_f32
__device__ __forceinline__ unsigned pk2(float a, float b) {
  __hip_bfloat162 h = __float22bfloat162_rn(float2{a, b});
  return *reinterpret_cast<unsigned*>(&h);
}

__global__ __launch_bounds__(256)
void sdpa_kernel(const float* __restrict__ qg, const float* __restrict__ kg,
                 const float* __restrict__ vg, const int* __restrict__ maskg,
                 float* __restrict__ outg, float* __restrict__ attng)
{
  __shared__ unsigned short Qs[QB][LDP];
  __shared__ unsigned short Ks[KT][LDP];
  __shared__ unsigned short Vt[DH][LDP];      // V transposed: [d][k]
  __shared__ unsigned short Ps[4][16][LDP];   // per-wave P tile
  __shared__ float invLds[QB];

  const int tid  = threadIdx.x;
  const int wid  = tid >> 6;
  const int lane = tid & 63;
  const int lrow = lane & 15;
  const int lhi  = lane >> 4;

  // grid order: blk = b*256 + qbi*16 + h  -> 16 heads sharing mask rows are adjacent
  const int blk = blockIdx.x;
  const int h   = blk & 15;
  const int qbi = (blk >> 4) & 15;
  const int b   = blk >> 8;
  const int bh  = b * 16 + h;

  const size_t qkv_off = (size_t)bh * (S_LEN * DH);
  const float* qb_ptr = qg + qkv_off + (size_t)qbi * QB * DH;
  const float* kb_ptr = kg + qkv_off;
  const float* vb_ptr = vg + qkv_off;
  const int*   mb_ptr = maskg + (size_t)b * (S_LEN * S_LEN);
  const int q0 = qbi * QB;
  const int qrow_l = wid * 16 + lhi * 4;

  const int* mlane = mb_ptr + (size_t)(q0 + qrow_l) * S_LEN + lrow;
  float* attn_base = attng + (size_t)bh * (S_LEN * S_LEN);
  float* alane = attn_base + (size_t)(q0 + qrow_l) * S_LEN + lrow;

  // ---- prologue: issue tile-0 K/V/mask loads into registers ----
  float4 Kp[4], Vp[4];
  int Mp[16], Mn[16];
  #pragma unroll
  for (int i = 0; i < 4; ++i) {
    int idx = tid + 256 * i;
    Kp[i] = *(const float4*)(kb_ptr + (size_t)(idx >> 4) * DH + ((idx & 15) << 2));
  }
  #pragma unroll
  for (int i = 0; i < 4; ++i) {
    int idx = tid + 256 * i;
    Vp[i] = *(const float4*)(vb_ptr + (size_t)(idx & 63) * DH + ((idx >> 6) << 2));
  }
  #pragma unroll
  for (int nt = 0; nt < 4; ++nt)
    #pragma unroll
    for (int r = 0; r < 4; ++r)
      Mp[nt * 4 + r] = mlane[(size_t)r * S_LEN + nt * 16];

  // ---- stage Q (f32 -> bf16) ----
  #pragma unroll
  for (int i = 0; i < 4; ++i) {
    int idx = tid + 256 * i;
    int row = idx >> 4, c4 = (idx & 15) << 2;
    float4 t = *(const float4*)(qb_ptr + row * DH + c4);
    uint2 w; w.x = pk2(t.x, t.y); w.y = pk2(t.z, t.w);
    *(uint2*)&Qs[row][c4] = w;
  }
  __syncthreads();
  const bf16x8 qf0 = *(const bf16x8*)&Qs[wid * 16 + lrow][lhi * 8];
  const bf16x8 qf1 = *(const bf16x8*)&Qs[wid * 16 + lrow][32 + lhi * 8];

  float rs[4] = {0.f, 0.f, 0.f, 0.f};
  f32x4 oacc[4];
  #pragma unroll
  for (int dt = 0; dt < 4; ++dt) oacc[dt] = (f32x4){0.f, 0.f, 0.f, 0.f};

  // ================= single pass over K tiles =================
  for (int kt = 0; kt < NKT; ++kt) {
    __syncthreads();   // prior compute done reading Ks/Vt

    // stage K (from prefetched regs)
    #pragma unroll
    for (int i = 0; i < 4; ++i) {
      int idx = tid + 256 * i;
      int row = idx >> 4, c4 = (idx & 15) << 2;
      float4 t = Kp[i];
      uint2 w; w.x = pk2(t.x, t.y); w.y = pk2(t.z, t.w);
      *(uint2*)&Ks[row][c4] = w;
    }
    // stage V transposed (from prefetched regs)
    #pragma unroll
    for (int i = 0; i < 4; ++i) {
      int idx = tid + 256 * i;
      int row = idx & 63, c4 = (idx >> 6) << 2;
      float4 t = Vp[i];
      Vt[c4 + 0][row] = f2bf(t.x);
      Vt[c4 + 1][row] = f2bf(t.y);
      Vt[c4 + 2][row] = f2bf(t.z);
      Vt[c4 + 3][row] = f2bf(t.w);
    }
    // issue next tile's global loads (hide latency under compute below)
    if (kt + 1 < NKT) {
      const float* kn = kb_ptr + (size_t)(kt + 1) * KT * DH;
      const float* vn = vb_ptr + (size_t)(kt + 1) * KT * DH;
      #pragma unroll
      for (int i = 0; i < 4; ++i) {
        int idx = tid + 256 * i;
        Kp[i] = *(const float4*)(kn + (size_t)(idx >> 4) * DH + ((idx & 15) << 2));
        Vp[i] = *(const float4*)(vn + (size_t)(idx & 63) * DH + ((idx >> 6) << 2));
      }
      #pragma unroll
      for (int nt = 0; nt < 4; ++nt)
        #pragma unroll
        for (int r = 0; r < 4; ++r)
          Mn[nt * 4 + r] = mlane[(size_t)r * S_LEN + (kt + 1) * KT + nt * 16];
    }
    __syncthreads();

    // QK^T + masked exp; write unnormalized attn; stash P (bf16) for PV
    #pragma unroll
    for (int nt = 0; nt < 4; ++nt) {
      bf16x8 kf0 = *(const bf16x8*)&Ks[nt * 16 + lrow][lhi * 8];
      bf16x8 kf1 = *(const bf16x8*)&Ks[nt * 16 + lrow][32 + lhi * 8];
      f32x4 acc = {0.f, 0.f, 0.f, 0.f};
      acc = __builtin_amdgcn_mfma_f32_16x16x32_bf16(qf0, kf0, acc, 0, 0, 0);
      acc = __builtin_amdgcn_mfma_f32_16x16x32_bf16(qf1, kf1, acc, 0, 0, 0);
      #pragma unroll
      for (int r = 0; r < 4; ++r) {
        float p = (Mp[nt * 4 + r] != 0) ? __expf(acc[r] * 0.125f) : 0.f;
        rs[r] += p;
        alane[(size_t)r * S_LEN + kt * KT + nt * 16] = p;   // unnormalized
        Ps[wid][lhi * 4 + r][nt * 16 + lrow] = f2bf(p);
      }
    }

    // PV (Ps is per-wave: no barrier needed; Vt protected by loop barriers)
    bf16x8 pf0 = *(const bf16x8*)&Ps[wid][lrow][lhi * 8];
    bf16x8 pf1 = *(const bf16x8*)&Ps[wid][lrow][32 + lhi * 8];
    #pragma unroll
    for (int dt = 0; dt < 4; ++dt) {
      bf16x8 vf0 = *(const bf16x8*)&Vt[dt * 16 + lrow][lhi * 8];
      bf16x8 vf1 = *(const bf16x8*)&Vt[dt * 16 + lrow][32 + lhi * 8];
      oacc[dt] = __builtin_amdgcn_mfma_f32_16x16x32_bf16(pf0, vf0, oacc[dt], 0, 0, 0);
      oacc[dt] = __builtin_amdgcn_mfma_f32_16x16x32_bf16(pf1, vf1, oacc[dt], 0, 0, 0);
    }

    if (kt + 1 < NKT) {
      #pragma unroll
      for (int j = 0; j < 16; ++j) Mp[j] = Mn[j];
    }
  }

  // ---- rowsum reduce across the 16 lanes sharing each q-row ----
  #pragma unroll
  for (int r = 0; r < 4; ++r) {
    float v = rs[r];
    v += __shfl_xor(v, 1);
    v += __shfl_xor(v, 2);
    v += __shfl_xor(v, 4);
    v += __shfl_xor(v, 8);
    rs[r] = v;
  }
  float inv[4];
  #pragma unroll
  for (int r = 0; r < 4; ++r) inv[r] = 1.0f / rs[r];

  // ---- out epilogue (registers only) ----
  #pragma unroll
  for (int dt = 0; dt < 4; ++dt)
    #pragma unroll
    for (int r = 0; r < 4; ++r)
      outg[qkv_off + (size_t)(q0 + qrow_l + r) * DH + dt * 16 + lrow] = oacc[dt][r] * inv[r];

  // ---- rescale attn in place (block-local; data should be L3-resident) ----
  if (lrow == 0) {
    #pragma unroll
    for (int r = 0; r < 4; ++r) invLds[qrow_l + r] = inv[r];
  }
  __syncthreads();   // drains our attn stores + publishes invLds

  float* ab = attn_base + (size_t)q0 * S_LEN;
  #pragma unroll 4
  for (int j = 0; j < 64; ++j) {
    int flat = tid + 256 * j;          // 64 rows x 256 float4
    int row = flat >> 8;
    int c4 = (flat & 255) << 2;
    float iv = invLds[row];
    float4 t = *(float4*)(ab + (size_t)row * S_LEN + c4);
    t.x *= iv; t.y *= iv; t.z *= iv; t.w *= iv;
    *(float4*)(ab + (size_t)row * S_LEN + c4) = t;
  }
}

extern "C" void kernel_launch(void* const* d_in, const int* in_sizes, int n_in,
                              void* d_out, int out_size, void* d_ws, size_t ws_size,
                              hipStream_t stream) {
  const float* q    = (const float*)d_in[0];
  const float* k    = (const float*)d_in[1];
  const float* v    = (const float*)d_in[2];
  const int*   mask = (const int*)d_in[3];
  float* out  = (float*)d_out;
  float* attn = out + (size_t)4 * 16 * 1024 * 64;   // output first, then attn
  sdpa_kernel<<<dim3(64 * 16), dim3(256), 0, stream>>>(q, k, v, mask, out, attn);
}

// Round 4
// 145.359 us; speedup vs baseline: 1.8839x; 1.8839x over previous
//
#include <hip/hip_runtime.h>
#include <hip/hip_bf16.h>

#define S_LEN 1024
#define DH 64
#define QB 64      // q rows per workgroup
#define KT 64      // k rows per tile
#define NKT 16     // S_LEN / KT
#define LDP 72     // padded LDS row length (bf16 elems)

typedef __attribute__((ext_vector_type(8))) short bf16x8;
typedef __attribute__((ext_vector_type(4))) float f32x4;
typedef unsigned long long u64;

__device__ __forceinline__ unsigned short f2bf(float f) {
  unsigned u = __float_as_uint(f);
  u = u + 0x7FFFu + ((u >> 16) & 1u);   // RNE
  return (unsigned short)(u >> 16);
}
__device__ __forceinline__ float bf2f(unsigned short s) {
  return __uint_as_float((unsigned)s << 16);
}
__device__ __forceinline__ unsigned pk2(float a, float b) {
  __hip_bfloat162 h = __float22bfloat162_rn(float2{a, b});
  return *reinterpret_cast<unsigned*>(&h);
}

// ---- pre-pass: pack int32 mask -> 1 bit/elem (one wave builds one u64 word) ----
__global__ __launch_bounds__(256)
void maskpack_kernel(const int* __restrict__ mask, u64* __restrict__ bits) {
  int w    = blockIdx.x * 4 + (threadIdx.x >> 6);
  int lane = threadIdx.x & 63;
  int m = mask[(size_t)w * 64 + lane];
  u64 word = __ballot(m != 0);
  if (lane == 0) bits[w] = word;
}

template<bool USE_BITS>
__global__ __launch_bounds__(256, 4)
void sdpa_kernel(const float* __restrict__ qg, const float* __restrict__ kg,
                 const float* __restrict__ vg, const int* __restrict__ maskg,
                 const u64* __restrict__ bitsg,
                 float* __restrict__ outg, float* __restrict__ attng)
{
  __shared__ unsigned short Qs[QB][LDP];
  __shared__ unsigned short Ks[KT][LDP];
  __shared__ unsigned short Vt[DH][LDP];      // V transposed: [d][k]
  __shared__ unsigned short Ps[4][16][LDP];   // per-wave P tile (bf16)
  __shared__ float invLds[QB];

  const int tid  = threadIdx.x;
  const int wid  = tid >> 6;
  const int lane = tid & 63;
  const int lrow = lane & 15;
  const int lhi  = lane >> 4;

  const int blk = blockIdx.x;
  const int qbi = blk & 15;
  const int bh  = blk >> 4;
  const int b   = bh >> 4;

  const size_t qkv_off = (size_t)bh * (S_LEN * DH);
  const float* qb_ptr = qg + qkv_off + (size_t)qbi * QB * DH;
  const float* kb_ptr = kg + qkv_off;
  const float* vb_ptr = vg + qkv_off;
  const int q0 = qbi * QB;
  const int qrow_l = wid * 16 + lhi * 4;

  // mask access bases for this lane's 4 rows
  const u64* bptr = bitsg + ((size_t)(b * S_LEN + q0 + qrow_l)) * NKT;  // + r*NKT + kt
  const int* mlane = maskg + (size_t)b * (S_LEN * S_LEN)
                   + (size_t)(q0 + qrow_l) * S_LEN + lrow;

  float* attn_base = attng + (size_t)bh * (S_LEN * S_LEN);

  // ---- prologue: issue tile-0 K + mask loads ----
  float4 Kp[4];
  u64 Bw[4], Bn[4];
  int Mp[16], Mn[16];
  #pragma unroll
  for (int i = 0; i < 4; ++i) {
    int idx = tid + 256 * i;
    Kp[i] = *(const float4*)(kb_ptr + (size_t)(idx >> 4) * DH + ((idx & 15) << 2));
  }
  if (USE_BITS) {
    #pragma unroll
    for (int r = 0; r < 4; ++r) Bw[r] = bptr[r * NKT + 0];
  } else {
    #pragma unroll
    for (int nt = 0; nt < 4; ++nt)
      #pragma unroll
      for (int r = 0; r < 4; ++r)
        Mp[nt * 4 + r] = mlane[(size_t)r * S_LEN + nt * 16];
  }

  // ---- stage Q (f32 -> bf16) ----
  #pragma unroll
  for (int i = 0; i < 4; ++i) {
    int idx = tid + 256 * i;
    int row = idx >> 4, c4 = (idx & 15) << 2;
    float4 t = *(const float4*)(qb_ptr + row * DH + c4);
    uint2 w; w.x = pk2(t.x, t.y); w.y = pk2(t.z, t.w);
    *(uint2*)&Qs[row][c4] = w;
  }
  __syncthreads();
  const bf16x8 qf0 = *(const bf16x8*)&Qs[wid * 16 + lrow][lhi * 8];
  const bf16x8 qf1 = *(const bf16x8*)&Qs[wid * 16 + lrow][32 + lhi * 8];

  // ================= pass 1: rowsums of exp(masked scores) =================
  float rs[4] = {0.f, 0.f, 0.f, 0.f};

  for (int kt = 0; kt < NKT; ++kt) {
    __syncthreads();
    #pragma unroll
    for (int i = 0; i < 4; ++i) {
      int idx = tid + 256 * i;
      int row = idx >> 4, c4 = (idx & 15) << 2;
      float4 t = Kp[i];
      uint2 w; w.x = pk2(t.x, t.y); w.y = pk2(t.z, t.w);
      *(uint2*)&Ks[row][c4] = w;
    }
    if (kt + 1 < NKT) {
      const float* kn = kb_ptr + (size_t)(kt + 1) * KT * DH;
      #pragma unroll
      for (int i = 0; i < 4; ++i) {
        int idx = tid + 256 * i;
        Kp[i] = *(const float4*)(kn + (size_t)(idx >> 4) * DH + ((idx & 15) << 2));
      }
      if (USE_BITS) {
        #pragma unroll
        for (int r = 0; r < 4; ++r) Bn[r] = bptr[r * NKT + kt + 1];
      } else {
        #pragma unroll
        for (int nt = 0; nt < 4; ++nt)
          #pragma unroll
          for (int r = 0; r < 4; ++r)
            Mn[nt * 4 + r] = mlane[(size_t)r * S_LEN + (kt + 1) * KT + nt * 16];
      }
    }
    __syncthreads();

    #pragma unroll
    for (int nt = 0; nt < 4; ++nt) {
      bf16x8 kf0 = *(const bf16x8*)&Ks[nt * 16 + lrow][lhi * 8];
      bf16x8 kf1 = *(const bf16x8*)&Ks[nt * 16 + lrow][32 + lhi * 8];
      f32x4 acc = {0.f, 0.f, 0.f, 0.f};
      acc = __builtin_amdgcn_mfma_f32_16x16x32_bf16(qf0, kf0, acc, 0, 0, 0);
      acc = __builtin_amdgcn_mfma_f32_16x16x32_bf16(qf1, kf1, acc, 0, 0, 0);
      #pragma unroll
      for (int r = 0; r < 4; ++r) {
        bool ok = USE_BITS ? (((Bw[r] >> (nt * 16 + lrow)) & 1ull) != 0)
                           : (Mp[nt * 4 + r] != 0);
        float p = ok ? __expf(acc[r] * 0.125f) : 0.f;
        rs[r] += p;
      }
    }
    if (kt + 1 < NKT) {
      if (USE_BITS) {
        #pragma unroll
        for (int r = 0; r < 4; ++r) Bw[r] = Bn[r];
      } else {
        #pragma unroll
        for (int j = 0; j < 16; ++j) Mp[j] = Mn[j];
      }
    }
  }

  // ---- rowsum reduce across the 16 lanes sharing each q-row ----
  #pragma unroll
  for (int r = 0; r < 4; ++r) {
    float v = rs[r];
    v += __shfl_xor(v, 1);
    v += __shfl_xor(v, 2);
    v += __shfl_xor(v, 4);
    v += __shfl_xor(v, 8);
    rs[r] = v;
  }
  float inv[4];
  #pragma unroll
  for (int r = 0; r < 4; ++r) inv[r] = 1.0f / rs[r];
  if (lrow == 0) {
    #pragma unroll
    for (int r = 0; r < 4; ++r) invLds[qrow_l + r] = inv[r];
  }

  // ---- prefetch pass-2 tile 0 (K, V, mask) ----
  float4 Vp[4];
  #pragma unroll
  for (int i = 0; i < 4; ++i) {
    int idx = tid + 256 * i;
    Kp[i] = *(const float4*)(kb_ptr + (size_t)(idx >> 4) * DH + ((idx & 15) << 2));
    Vp[i] = *(const float4*)(vb_ptr + (size_t)(idx & 63) * DH + ((idx >> 6) << 2));
  }
  if (USE_BITS) {
    #pragma unroll
    for (int r = 0; r < 4; ++r) Bw[r] = bptr[r * NKT + 0];
  } else {
    #pragma unroll
    for (int nt = 0; nt < 4; ++nt)
      #pragma unroll
      for (int r = 0; r < 4; ++r)
        Mp[nt * 4 + r] = mlane[(size_t)r * S_LEN + nt * 16];
  }

  f32x4 oacc[4];
  #pragma unroll
  for (int dt = 0; dt < 4; ++dt) oacc[dt] = (f32x4){0.f, 0.f, 0.f, 0.f};

  // ================= pass 2: recompute, write normalized attn, PV =================
  for (int kt = 0; kt < NKT; ++kt) {
    __syncthreads();   // prior tile's consumers of Ks/Vt/Ps done (also publishes invLds on kt==0)

    #pragma unroll
    for (int i = 0; i < 4; ++i) {
      int idx = tid + 256 * i;
      int row = idx >> 4, c4 = (idx & 15) << 2;
      float4 t = Kp[i];
      uint2 w; w.x = pk2(t.x, t.y); w.y = pk2(t.z, t.w);
      *(uint2*)&Ks[row][c4] = w;
    }
    #pragma unroll
    for (int i = 0; i < 4; ++i) {
      int idx = tid + 256 * i;
      int row = idx & 63, c4 = (idx >> 6) << 2;
      float4 t = Vp[i];
      Vt[c4 + 0][row] = f2bf(t.x);
      Vt[c4 + 1][row] = f2bf(t.y);
      Vt[c4 + 2][row] = f2bf(t.z);
      Vt[c4 + 3][row] = f2bf(t.w);
    }
    if (kt + 1 < NKT) {
      const float* kn = kb_ptr + (size_t)(kt + 1) * KT * DH;
      const float* vn = vb_ptr + (size_t)(kt + 1) * KT * DH;
      #pragma unroll
      for (int i = 0; i < 4; ++i) {
        int idx = tid + 256 * i;
        Kp[i] = *(const float4*)(kn + (size_t)(idx >> 4) * DH + ((idx & 15) << 2));
        Vp[i] = *(const float4*)(vn + (size_t)(idx & 63) * DH + ((idx >> 6) << 2));
      }
      if (USE_BITS) {
        #pragma unroll
        for (int r = 0; r < 4; ++r) Bn[r] = bptr[r * NKT + kt + 1];
      } else {
        #pragma unroll
        for (int nt = 0; nt < 4; ++nt)
          #pragma unroll
          for (int r = 0; r < 4; ++r)
            Mn[nt * 4 + r] = mlane[(size_t)r * S_LEN + (kt + 1) * KT + nt * 16];
      }
    }
    __syncthreads();

    // QK^T + masked exp -> per-wave bf16 P tile
    #pragma unroll
    for (int nt = 0; nt < 4; ++nt) {
      bf16x8 kf0 = *(const bf16x8*)&Ks[nt * 16 + lrow][lhi * 8];
      bf16x8 kf1 = *(const bf16x8*)&Ks[nt * 16 + lrow][32 + lhi * 8];
      f32x4 acc = {0.f, 0.f, 0.f, 0.f};
      acc = __builtin_amdgcn_mfma_f32_16x16x32_bf16(qf0, kf0, acc, 0, 0, 0);
      acc = __builtin_amdgcn_mfma_f32_16x16x32_bf16(qf1, kf1, acc, 0, 0, 0);
      #pragma unroll
      for (int r = 0; r < 4; ++r) {
        bool ok = USE_BITS ? (((Bw[r] >> (nt * 16 + lrow)) & 1ull) != 0)
                           : (Mp[nt * 4 + r] != 0);
        float p = ok ? __expf(acc[r] * 0.125f) : 0.f;
        Ps[wid][lhi * 4 + r][nt * 16 + lrow] = f2bf(p);
      }
    }

    // PV (per-wave Ps; Vt protected by loop barriers)
    bf16x8 pf0 = *(const bf16x8*)&Ps[wid][lrow][lhi * 8];
    bf16x8 pf1 = *(const bf16x8*)&Ps[wid][lrow][32 + lhi * 8];
    #pragma unroll
    for (int dt = 0; dt < 4; ++dt) {
      bf16x8 vf0 = *(const bf16x8*)&Vt[dt * 16 + lrow][lhi * 8];
      bf16x8 vf1 = *(const bf16x8*)&Vt[dt * 16 + lrow][32 + lhi * 8];
      oacc[dt] = __builtin_amdgcn_mfma_f32_16x16x32_bf16(pf0, vf0, oacc[dt], 0, 0, 0);
      oacc[dt] = __builtin_amdgcn_mfma_f32_16x16x32_bf16(pf1, vf1, oacc[dt], 0, 0, 0);
    }

    // normalized attn store: wave writes its 16 rows x 64 cols as float4 rows
    {
      float* ab = attn_base + (size_t)(q0 + wid * 16) * S_LEN + kt * KT;
      #pragma unroll
      for (int j = 0; j < 4; ++j) {
        int flat = lane + 64 * j;
        int rowl = flat >> 4;
        int c4   = (flat & 15) << 2;
        float iv = invLds[wid * 16 + rowl];
        const unsigned short* pr = &Ps[wid][rowl][c4];
        float4 st;
        st.x = bf2f(pr[0]) * iv;
        st.y = bf2f(pr[1]) * iv;
        st.z = bf2f(pr[2]) * iv;
        st.w = bf2f(pr[3]) * iv;
        *(float4*)(ab + (size_t)rowl * S_LEN + c4) = st;
      }
    }

    if (kt + 1 < NKT) {
      if (USE_BITS) {
        #pragma unroll
        for (int r = 0; r < 4; ++r) Bw[r] = Bn[r];
      } else {
        #pragma unroll
        for (int j = 0; j < 16; ++j) Mp[j] = Mn[j];
      }
    }
  }

  // ---- out epilogue ----
  #pragma unroll
  for (int dt = 0; dt < 4; ++dt)
    #pragma unroll
    for (int r = 0; r < 4; ++r)
      outg[qkv_off + (size_t)(q0 + qrow_l + r) * DH + dt * 16 + lrow] = oacc[dt][r] * inv[r];
}

extern "C" void kernel_launch(void* const* d_in, const int* in_sizes, int n_in,
                              void* d_out, int out_size, void* d_ws, size_t ws_size,
                              hipStream_t stream) {
  const float* q    = (const float*)d_in[0];
  const float* k    = (const float*)d_in[1];
  const float* v    = (const float*)d_in[2];
  const int*   mask = (const int*)d_in[3];
  float* out  = (float*)d_out;
  float* attn = out + (size_t)4 * 16 * 1024 * 64;

  const size_t nwords = (size_t)4 * S_LEN * NKT;    // 65536 u64 = 512 KB
  if (ws_size >= nwords * sizeof(u64)) {
    u64* bits = (u64*)d_ws;
    maskpack_kernel<<<dim3(nwords / 4), dim3(256), 0, stream>>>(mask, bits);
    sdpa_kernel<true><<<dim3(64 * 16), dim3(256), 0, stream>>>(q, k, v, mask, bits, out, attn);
  } else {
    sdpa_kernel<false><<<dim3(64 * 16), dim3(256), 0, stream>>>(q, k, v, mask, nullptr, out, attn);
  }
}